// Round 6
// baseline (809.358 us; speedup 1.0000x reference)
//
#include <hip/hip_runtime.h>

// Problem constants
#define T_STEPS 100
#define BATCH   512
#define D0      700
#define D1      512
#define D2      20
#define M_ROWS  (T_STEPS * BATCH)   // 51200

// Output layout (floats): [s2 (T*B*20) | s1 (T*B*512) | s2 copy (T*B*20)]
#define OFF_S2A 0
#define OFF_S1  (T_STEPS * BATCH * D2)                    // 1,024,000
#define OFF_S2B (OFF_S1 + T_STEPS * BATCH * D1)           // 27,238,400

__device__ __constant__ const float kALPHA = 0.8f;
__device__ __constant__ const float kBETA  = 0.9f;
__device__ __constant__ const float kTHR   = 1.0f;

// ---------------------------------------------------------------------------
// GEMM1: C[M,512] = A[M,700] * W1[512,700]^T  (row-major, K contiguous)
// 128x128 tile, BK=32, 256 threads, 8x8 microtile.
//
// NEW (R6): global_load_lds staging + double-buffered 2-phase pipeline.
//  - LDS tiles are [m][chunk] row-major (128 rows x 8 chunks of 16B), the
//    layout global_load_lds can write (wave-uniform LDS base + lane*16B:
//    lane l -> row +(l>>3), chunk (l&7)).
//  - Bank-conflict fix via SOURCE pre-swizzle (LDS stays linear): position
//    cl holds k-chunk (cl ^ g(row)), g(row) = (row>>3)&7. Compute reads
//    chunk c at position c^g. Verified: A-frag b64 reads = 4 distinct banks
//    (free), B-frag = 2 addrs/bank (free, m136), staging = HW-linear.
//  - Per tile: issue next tile's 8 global_load_lds per wave, compute current
//    from LDS, one __syncthreads() (vmcnt drain) per tile. Loads have the
//    whole ~4096-cycle FMA phase to land.
//  - k-edge: 700 = 21*32 + 28. Chunk-7 source addr of the last tile is
//    clamped to byte 2784 (in-bounds); compute<14 pairs> never reads it.
//  - fmaf chain stays ascending-k, single accumulator -> bitwise-identical
//    to rounds 1-5 (absmax 0.0).
// Grid swizzle kept from R4 (FETCH 287->102MB): XCD x = id%8 owns row-panels
// [50x,50x+50), col fastest.
// ---------------------------------------------------------------------------
constexpr int BM = 128, BN = 128, BK = 32;
constexpr int TILE_F = BM * BK;          // 4096 floats = 16KB

#define HAS_GLL (__has_builtin(__builtin_amdgcn_global_load_lds))

__device__ __forceinline__ void stage_tile(const float* __restrict__ gbase,
                                           int row0, int kt, float* lbuf,
                                           int wave, int lane) {
#pragma unroll
    for (int s = 0; s < 4; ++s) {
        const int rloc = wave * 32 + s * 8;          // wave-uniform row base
        const int gws  = (wave * 4 + s) & 7;         // wave-uniform swizzle
        int koff = kt * 128 + (((lane & 7) ^ gws) << 4);   // bytes within row
        koff = koff > 2784 ? 2784 : koff;            // clamp (last tile chunk7)
        const float* g = (const float*)((const char*)gbase
                         + (size_t)(row0 + rloc + (lane >> 3)) * 2800 + koff);
        float* l = lbuf + rloc * 32;                 // wave-uniform LDS base
#if HAS_GLL
        __builtin_amdgcn_global_load_lds(
            (const __attribute__((address_space(1))) void*)g,
            (__attribute__((address_space(3))) void*)l, 16, 0, 0);
#else
        float4 v = *(const float4*)g;
        *(float4*)&l[lane * 4] = v;
#endif
    }
}

template <int NP>
__device__ __forceinline__ void compute_tile(const float* __restrict__ As,
                                             const float* __restrict__ Ws,
                                             int ty, int tx,
                                             float acc[8][8]) {
    const int tyg = ty & 7, txg = tx & 7;
#pragma unroll
    for (int p = 0; p < NP; ++p) {
        const int c = p >> 1;             // 16B chunk
        const int e = (p & 1) << 1;       // float offset within chunk pair
        float2 av[8], bv[8];
#pragma unroll
        for (int i = 0; i < 8; ++i)
            av[i] = *(const float2*)&As[(ty * 8 + i) * 32 + ((c ^ tyg) << 2) + e];
#pragma unroll
        for (int j = 0; j < 8; ++j)
            bv[j] = *(const float2*)&Ws[(tx * 8 + j) * 32 + ((c ^ txg) << 2) + e];
        // k = 2p  (ascending-k fmaf chain: bitwise-stable)
#pragma unroll
        for (int i = 0; i < 8; ++i)
#pragma unroll
            for (int j = 0; j < 8; ++j)
                acc[i][j] = fmaf(av[i].x, bv[j].x, acc[i][j]);
        // k = 2p+1
#pragma unroll
        for (int i = 0; i < 8; ++i)
#pragma unroll
            for (int j = 0; j < 8; ++j)
                acc[i][j] = fmaf(av[i].y, bv[j].y, acc[i][j]);
    }
}

__global__ __launch_bounds__(256)
void gemm1_kernel(const float* __restrict__ A, const float* __restrict__ W,
                  float* __restrict__ C) {
    __shared__ float As[2][TILE_F];
    __shared__ float Ws[2][TILE_F];

    // XCD-chunked remap: 1600 blocks, 8 XCDs, 200 each; col fastest.
    const int d     = blockIdx.x;
    const int xcd   = d & 7;
    const int local = d >> 3;              // 0..199
    const int brow  = xcd * 50 + (local >> 2);
    const int bcol  = local & 3;

    const int tid  = threadIdx.x;
    const int row0 = brow * BM;
    const int col0 = bcol * BN;
    const int wave = tid >> 6;
    const int lane = tid & 63;
    const int tx   = tid & 15;
    const int ty   = tid >> 4;

    float acc[8][8];
#pragma unroll
    for (int i = 0; i < 8; ++i)
#pragma unroll
        for (int j = 0; j < 8; ++j) acc[i][j] = 0.f;

    const int NT = 22;   // 21 full 32-k tiles + one 28-k tile

    // prologue: stage tile 0
    stage_tile(A, row0, 0, As[0], wave, lane);
    stage_tile(W, col0, 0, Ws[0], wave, lane);
    __syncthreads();

    int buf = 0;
    for (int kt = 0; kt < NT; ++kt) {
        if (kt + 1 < NT) {
            stage_tile(A, row0, kt + 1, As[buf ^ 1], wave, lane);
            stage_tile(W, col0, kt + 1, Ws[buf ^ 1], wave, lane);
        }
        if (kt + 1 < NT)
            compute_tile<16>(As[buf], Ws[buf], ty, tx, acc);
        else
            compute_tile<14>(As[buf], Ws[buf], ty, tx, acc);   // 28 k
        __syncthreads();   // drains vmcnt -> next buffer ready; buf reusable
        buf ^= 1;
    }

#pragma unroll
    for (int i = 0; i < 8; ++i) {
        float* cp = C + (size_t)(row0 + ty * 8 + i) * D1 + col0 + tx * 8;
        float4 v0 = make_float4(acc[i][0], acc[i][1], acc[i][2], acc[i][3]);
        float4 v1 = make_float4(acc[i][4], acc[i][5], acc[i][6], acc[i][7]);
        *(float4*)(cp + 0) = v0;
        *(float4*)(cp + 4) = v1;
    }
}

// ---------------------------------------------------------------------------
// Scan 1: in-place over pre1 buffer [T, B*512]; each thread owns one neuron.
// ---------------------------------------------------------------------------
__global__ __launch_bounds__(256)
void scan1_kernel(float* __restrict__ buf) {
#pragma clang fp contract(off)
    const int idx = blockIdx.x * blockDim.x + threadIdx.x;  // 0 .. 262143
    const int stride = BATCH * D1;
    float syn = 0.f, mem = 0.f;
    float* p = buf + idx;
    for (int t = 0; t < T_STEPS; ++t) {
        const float pre = p[(size_t)t * stride];
        float a = kALPHA * syn;
        syn = a + pre;
        const float reset = (mem > kTHR) ? 1.f : 0.f;
        float bm = kBETA * mem;
        mem = (bm + syn) * (1.f - reset);
        p[(size_t)t * stride] = (mem > kTHR) ? 1.f : 0.f;
    }
}

// ---------------------------------------------------------------------------
// GEMM2: C[M,20] = S1[M,512] * W2[20,512]^T.  W2 staged in LDS (40 KB).
// 256 threads = 64 rows x 4 k-quarters; shuffle-reduce across the 4.
// ---------------------------------------------------------------------------
__global__ __launch_bounds__(256)
void gemm2_kernel(const float* __restrict__ S1, const float* __restrict__ W2,
                  float* __restrict__ C) {
    __shared__ float Wsh[D2 * D1];  // 10240 floats = 40 KB
    for (int i = threadIdx.x; i < (D2 * D1) / 4; i += 256)
        ((float4*)Wsh)[i] = ((const float4*)W2)[i];
    __syncthreads();

    const int r  = threadIdx.x >> 2;   // 0..63
    const int kq = threadIdx.x & 3;    // k quarter (128 each)
    const int m  = blockIdx.x * 64 + r;

    const float4* src = (const float4*)(S1 + (size_t)m * D1 + kq * 128);
    float acc[D2];
#pragma unroll
    for (int o = 0; o < D2; ++o) acc[o] = 0.f;

    for (int j = 0; j < 32; ++j) {
        const float4 v = src[j];
        const float* wbase = Wsh + kq * 128 + j * 4;
#pragma unroll
        for (int o = 0; o < D2; ++o) {
            const float4 w = *(const float4*)(wbase + o * D1);
            acc[o] += v.x * w.x + v.y * w.y + v.z * w.z + v.w * w.w;
        }
    }
    // reduce over the 4 k-quarters (consecutive lanes)
#pragma unroll
    for (int o = 0; o < D2; ++o) {
        acc[o] += __shfl_xor(acc[o], 1);
        acc[o] += __shfl_xor(acc[o], 2);
    }
    if (kq == 0) {
        float* cp = C + (size_t)m * D2;
#pragma unroll
        for (int o = 0; o < D2; o += 4)
            *(float4*)(cp + o) = make_float4(acc[o], acc[o + 1], acc[o + 2], acc[o + 3]);
    }
}

// ---------------------------------------------------------------------------
// Scan 2: in-place over pre2 [T, B*20]; also writes the duplicate s2 slot.
// ---------------------------------------------------------------------------
__global__ __launch_bounds__(256)
void scan2_kernel(float* __restrict__ buf, float* __restrict__ dup) {
#pragma clang fp contract(off)
    const int idx = blockIdx.x * blockDim.x + threadIdx.x;  // 0 .. 10239
    const int stride = BATCH * D2;
    float syn = 0.f, mem = 0.f;
    for (int t = 0; t < T_STEPS; ++t) {
        const size_t off = (size_t)t * stride + idx;
        const float pre = buf[off];
        float a = kALPHA * syn;
        syn = a + pre;
        const float reset = (mem > kTHR) ? 1.f : 0.f;
        float bm = kBETA * mem;
        mem = (bm + syn) * (1.f - reset);
        const float s = (mem > kTHR) ? 1.f : 0.f;
        buf[off] = s;
        dup[off] = s;
    }
}

// ---------------------------------------------------------------------------
extern "C" void kernel_launch(void* const* d_in, const int* in_sizes, int n_in,
                              void* d_out, int out_size, void* d_ws, size_t ws_size,
                              hipStream_t stream) {
    const float* x  = (const float*)d_in[0];   // [100, 512, 700]
    const float* W1 = (const float*)d_in[1];   // [512, 700]
    const float* W2 = (const float*)d_in[2];   // [20, 512]
    float* out = (float*)d_out;

    float* s2a = out + OFF_S2A;   // [T,B,20]  (pre2 then s2)
    float* s1  = out + OFF_S1;    // [T,B,512] (pre1 then s1)
    float* s2b = out + OFF_S2B;   // [T,B,20]  duplicate s2

    // 1) pre1 = x @ W1^T  -> s1 slot  (1-D grid, XCD-chunked swizzle inside)
    gemm1_kernel<<<(M_ROWS / BM) * (D1 / BN), 256, 0, stream>>>(x, W1, s1);

    // 2) scan layer 1 in place (pre1 -> spikes)
    scan1_kernel<<<(BATCH * D1) / 256, 256, 0, stream>>>(s1);

    // 3) pre2 = s1 @ W2^T -> s2a slot
    gemm2_kernel<<<M_ROWS / 64, 256, 0, stream>>>(s1, W2, s2a);

    // 4) scan layer 2 in place + duplicate
    scan2_kernel<<<(BATCH * D2) / 256, 256, 0, stream>>>(s2a, s2b);
}